// Round 8
// baseline (279.879 us; speedup 1.0000x reference)
//
#include <hip/hip_runtime.h>
#include <math.h>

// Problem constants
#define N_TOK  16384   // B*S
#define D_IN   1024
#define D_OUT  1024
#define N_CENT 1024

// GEMM tiling
#define BM 128
#define BN 128
#define BK 64
#define NTILE (N_CENT / BN)   // 8

// Margin: bf16 approx error on d2 max ~1.6e-2 over all pairs; TAU >= 2*maxerr
// guarantees (a) unique-gap argmin exact, (b) candidate set {d2a <= gmin+TAU}
// contains the exact argmin. TAU=0.05 validated R3/R4/R5/R7 (absmax 0).
#define TAU 0.05f

#define SENT 0xFFFFFFFFFFFFFFFFull

typedef __attribute__((ext_vector_type(8))) short short8;
typedef __attribute__((ext_vector_type(4))) float float4v;
typedef unsigned int u32;
typedef unsigned short u16;
typedef unsigned long long u64;

__device__ __forceinline__ void async_copy16(const void* g, void* l) {
    __builtin_amdgcn_global_load_lds(
        (const __attribute__((address_space(1))) u32*)g,
        (__attribute__((address_space(3))) u32*)l, 16, 0, 0);
}

__device__ __forceinline__ u16 f32_to_bf16_rne(float f) {
    u32 u = __float_as_uint(f);
    u32 r = (u + 0x7FFFu + ((u >> 16) & 1u)) >> 16;
    return (u16)r;
}

__device__ __forceinline__ u64 umin64(u64 a, u64 b) { return a < b ? a : b; }
__device__ __forceinline__ u64 umax64(u64 a, u64 b) { return a > b ? a : b; }
__device__ __forceinline__ float pk_val(u64 p) { return __uint_as_float((u32)(p >> 32)); }

// Merge two ascending-sorted u64 triples into (s1,s2,s3).
// Packed key (d2_bits<<32)|idx with d2>0: u64 order == lex (val, idx) ==
// numpy first-occurrence argmin tie-break (validated by R7's atomicMin).
// Network: o1=min(a1,b1); o2=min(max(a1,b1),min(a2,b2));
//          o3=min(max(max(a1,b1),min(a2,b2)), min(a3,b3)).
__device__ __forceinline__ void merge3u(
    u64& s1, u64& s2, u64& s3, u64 b1, u64 b2, u64 b3)
{
    const u64 m1 = umin64(s1, b1);
    const u64 M1 = umax64(s1, b1);
    const u64 m2 = umin64(s2, b2);
    const u64 m3 = umin64(s3, b3);
    s1 = m1;
    const u64 t2 = umin64(M1, m2);
    s3 = umin64(umax64(M1, m2), m3);
    s2 = t2;
}

// Wave dot product, summation order identical to R5/R7-validated rescore.
__device__ __forceinline__ float wave_dot(
    const float* __restrict__ X, const float* __restrict__ C,
    int m, int n, int l)
{
    const float4* xr = (const float4*)(X + (size_t)m * D_IN);
    const float4* cr = (const float4*)(C + (size_t)n * D_IN);
    float p = 0.f;
#pragma unroll
    for (int k = 0; k < 4; ++k) {
        const float4 cv = cr[l + 64 * k];
        const float4 xv = xr[l + 64 * k];
        p = fmaf(xv.x, cv.x, p); p = fmaf(xv.y, cv.y, p);
        p = fmaf(xv.z, cv.z, p); p = fmaf(xv.w, cv.w, p);
    }
#pragma unroll
    for (int off = 32; off > 0; off >>= 1) p += __shfl_xor(p, off);
    return p;
}

// ---------------------------------------------------------------------------
// Fused fp32->bf16 convert + row norms for X and C + counter zeroing.
// ---------------------------------------------------------------------------
__global__ __launch_bounds__(256) void prep_kernel(
    const float* __restrict__ X, const float* __restrict__ C,
    u16* __restrict__ Xh, u16* __restrict__ Ch,
    float* __restrict__ xsq, float* __restrict__ csq,
    int* __restrict__ ctrs)
{
    // ctrs[0]=wcount, ctrs[1]=ovfcount, ctrs[2..129]=per-mtile done tickets
    if (blockIdx.x == 0 && threadIdx.x < 2 + (N_TOK / BM))
        ctrs[threadIdx.x] = 0;

    const int wv = threadIdx.x >> 6;
    const int l  = threadIdx.x & 63;
    int row = blockIdx.x * 4 + wv;
    const float* src; u16* dsth; float* dsts;
    if (row < N_TOK) { src = X; dsth = Xh; dsts = xsq; }
    else { row -= N_TOK; src = C; dsth = Ch; dsts = csq; }
    const float4* xr = (const float4*)(src + (size_t)row * D_IN);
    ushort4* hr = (ushort4*)(dsth + (size_t)row * D_IN);
    float s = 0.f;
#pragma unroll
    for (int i = 0; i < 4; ++i) {
        float4 v = xr[l + i * 64];
        ushort4 o;
        o.x = f32_to_bf16_rne(v.x); o.y = f32_to_bf16_rne(v.y);
        o.z = f32_to_bf16_rne(v.z); o.w = f32_to_bf16_rne(v.w);
        hr[l + i * 64] = o;
        s += v.x * v.x + v.y * v.y + v.z * v.z + v.w * v.w;
    }
#pragma unroll
    for (int off = 32; off > 0; off >>= 1) s += __shfl_down(s, off);
    if (l == 0) dsts[row] = s;
}

// ---------------------------------------------------------------------------
// bf16 MFMA GEMM + fused per-tile top-3 epilogue (u64-packed) + fused
// per-m-tile final reduce via last-block ticket (rocPRIM pattern).
// ---------------------------------------------------------------------------
__global__ __launch_bounds__(256, 4) void gemm_fused_kernel(
    const u16* __restrict__ Xh, const u16* __restrict__ Ch,
    const float* __restrict__ x_sq, const float* __restrict__ c_sq,
    u64* __restrict__ pt1, u64* __restrict__ pt2, u64* __restrict__ pt3,
    int* __restrict__ idx_final, u64* __restrict__ packed,
    u32* __restrict__ work, int* __restrict__ ovf_list,
    int* __restrict__ ctrs)
{
    __shared__ __align__(16) u16 As[BM * BK];   // 16 KB
    __shared__ __align__(16) u16 Bs[BN * BK];   // 16 KB
    __shared__ int lastflag;

    const int t  = threadIdx.x;
    const int w  = t >> 6;
    const int l  = t & 63;
    const int wi = w >> 1, wj = w & 1;
    const int m0 = blockIdx.x * BM;
    const int n0 = blockIdx.y * BN;
    const int quad = l >> 4;
    const int r15  = l & 15;

    float4v acc[4][4];
#pragma unroll
    for (int i = 0; i < 4; ++i)
#pragma unroll
        for (int j = 0; j < 4; ++j)
            acc[i][j] = (float4v){0.f, 0.f, 0.f, 0.f};

    for (int k0 = 0; k0 < D_IN; k0 += BK) {
#pragma unroll
        for (int r = 0; r < 4; ++r) {
            const int s   = r * 256 + t;
            const int row = s >> 3;
            const int q   = (s & 7) ^ (row & 7);
            async_copy16(Xh + (size_t)(m0 + row) * D_IN + k0 + q * 8, As + s * 8);
            async_copy16(Ch + (size_t)(n0 + row) * D_IN + k0 + q * 8, Bs + s * 8);
        }
        __syncthreads();
#pragma unroll
        for (int kk2 = 0; kk2 < 2; ++kk2) {
            short8 af[4], bfr[4];
#pragma unroll
            for (int i = 0; i < 4; ++i) {
                const int r = wi * 64 + i * 16 + r15;
                af[i] = *(const short8*)(As + (r * 8 + ((kk2 * 4 + quad) ^ (r & 7))) * 8);
            }
#pragma unroll
            for (int j = 0; j < 4; ++j) {
                const int r = wj * 64 + j * 16 + r15;
                bfr[j] = *(const short8*)(Bs + (r * 8 + ((kk2 * 4 + quad) ^ (r & 7))) * 8);
            }
#pragma unroll
            for (int i = 0; i < 4; ++i)
#pragma unroll
                for (int j = 0; j < 4; ++j)
                    acc[i][j] = __builtin_amdgcn_mfma_f32_16x16x32_bf16(
                        af[i], bfr[j], acc[i][j], 0, 0, 0);
        }
        __syncthreads();
    }

    // --- Epilogue: per-64-col-subtile top-3 (u64-packed), then cross-wave merge.
    u64* red = (u64*)As;   // [BM][2] triples = 6144 B, reuses staging arena

    const int nbase = n0 + wj * 64 + r15;
    float cq[4];
#pragma unroll
    for (int j = 0; j < 4; ++j) cq[j] = c_sq[nbase + j * 16];

#pragma unroll
    for (int i = 0; i < 4; ++i) {
#pragma unroll
        for (int reg = 0; reg < 4; ++reg) {
            const int rloc = wi * 64 + i * 16 + quad * 4 + reg;
            const float xq = x_sq[m0 + rloc];
            const float d0 = (xq - 2.0f * acc[i][0][reg]) + cq[0];
            u64 s1 = ((u64)__float_as_uint(d0) << 32) | (u32)nbase;
            u64 s2 = SENT, s3 = SENT;
#pragma unroll
            for (int j = 1; j < 4; ++j) {
                const float dj = (xq - 2.0f * acc[i][j][reg]) + cq[j];
                const u64 v = ((u64)__float_as_uint(dj) << 32) | (u32)(nbase + j * 16);
                if (v < s1)      { s3 = s2; s2 = s1; s1 = v; }
                else if (v < s2) { s3 = s2; s2 = v; }
                else if (v < s3) { s3 = v; }
            }
#pragma unroll
            for (int off = 1; off < 16; off <<= 1) {
                const u64 b1 = __shfl_xor(s1, off);
                const u64 b2 = __shfl_xor(s2, off);
                const u64 b3 = __shfl_xor(s3, off);
                merge3u(s1, s2, s3, b1, b2, b3);
            }
            if (r15 == 0) {
                red[(rloc * 2 + wj) * 3 + 0] = s1;
                red[(rloc * 2 + wj) * 3 + 1] = s2;
                red[(rloc * 2 + wj) * 3 + 2] = s3;
            }
        }
    }
    __syncthreads();
    if (t < BM) {
        u64 a1 = red[(t * 2) * 3], a2 = red[(t * 2) * 3 + 1], a3 = red[(t * 2) * 3 + 2];
        merge3u(a1, a2, a3,
                red[(t * 2 + 1) * 3], red[(t * 2 + 1) * 3 + 1], red[(t * 2 + 1) * 3 + 2]);
        const size_t o = (size_t)blockIdx.y * N_TOK + m0 + t;
        pt1[o] = a1; pt2[o] = a2; pt3[o] = a3;
    }

    // --- Ticket: last block of this m-tile performs the cross-tile reduce.
    __threadfence();                       // release our pt writes (device scope)
    __syncthreads();
    if (t == 0)
        lastflag = (atomicAdd(&ctrs[2 + blockIdx.x], 1) == NTILE - 1) ? 1 : 0;
    __syncthreads();
    if (!lastflag) return;
    __threadfence();                       // acquire other tiles' pt writes

    if (t < BM) {
        const int m = m0 + t;
        u64 t1[NTILE], t2[NTILE], t3[NTILE];
#pragma unroll
        for (int q = 0; q < NTILE; ++q) {
            t1[q] = pt1[(size_t)q * N_TOK + m];
            t2[q] = pt2[(size_t)q * N_TOK + m];
            t3[q] = pt3[(size_t)q * N_TOK + m];
        }
        u64 g1 = t1[0], g2 = t2[0], g3 = t3[0];
#pragma unroll
        for (int q = 1; q < NTILE; ++q) merge3u(g1, g2, g3, t1[q], t2[q], t3[q]);

        const float thr = pk_val(g1) + TAU;
        idx_final[m] = (int)(g1 & 1023u);
        packed[m] = SENT;

        // Exact completeness: per-tile v3 vs thr (NOT global v3 -- that
        // over-flags; R4 lesson).
        bool ovf = false;
#pragma unroll
        for (int q = 0; q < NTILE; ++q)
            if (pk_val(t3[q]) <= thr) ovf = true;

        if (ovf) {
            const int pos = atomicAdd(&ctrs[1], 1);
            ovf_list[pos] = m;
        } else if (pk_val(g2) <= thr) {
            int k = 0; u32 cd[2 * NTILE];
#pragma unroll
            for (int q = 0; q < NTILE; ++q) {
                if (pk_val(t1[q]) <= thr) cd[k++] = (u32)(t1[q] & 1023u);
                if (pk_val(t2[q]) <= thr) cd[k++] = (u32)(t2[q] & 1023u);
            }
            const int base = atomicAdd(&ctrs[0], k);
            for (int i = 0; i < k; ++i)
                work[base + i] = ((u32)m << 10) | cd[i];
        }
    }
}

// ---------------------------------------------------------------------------
// Exact fp32 rescore, unified: grid-stride over cand items then ovf items,
// one wave per item. u64 atomicMin == lex (val, idx) (R7-validated).
// ---------------------------------------------------------------------------
__global__ __launch_bounds__(256) void rescore_kernel(
    const float* __restrict__ X, const float* __restrict__ C,
    const float* __restrict__ x_sq, const float* __restrict__ c_sq,
    const u32* __restrict__ work, const int* __restrict__ ovf_list,
    const int* __restrict__ ctrs, u64* __restrict__ packed)
{
    const int l = threadIdx.x & 63;
    const int nw   = ctrs[0];
    const int novf = ctrs[1];
    const int total = nw + (novf << 10);
    const int wgid   = blockIdx.x * 4 + (threadIdx.x >> 6);
    const int nwaves = gridDim.x * 4;

    for (int i = wgid; i < total; i += nwaves) {
        int m, n;
        if (i < nw) {
            const u32 item = work[i];
            m = (int)(item >> 10); n = (int)(item & 1023u);
        } else {
            const int j = i - nw;
            m = ovf_list[j >> 10]; n = j & 1023;
        }
        const float p = wave_dot(X, C, m, n, l);
        if (l == 0) {
            const float d2 = (x_sq[m] - 2.0f * p) + c_sq[n];
            const u64 pk = ((u64)__float_as_uint(d2) << 32) | (u32)n;
            atomicMin(&packed[m], pk);
        }
    }
}

// ---------------------------------------------------------------------------
// Gather + bias, with fused writeback. One wave per token, 4 tokens/block.
// ---------------------------------------------------------------------------
__global__ __launch_bounds__(256) void gather_kernel(
    const int* __restrict__ idx_final, const u64* __restrict__ packed,
    const float* __restrict__ table, const float* __restrict__ bias,
    float* __restrict__ out)
{
    const int wv = threadIdx.x >> 6;
    const int l  = threadIdx.x & 63;
    const int m  = blockIdx.x * 4 + wv;
    const u64 pk = packed[m];
    const int bi = (pk != SENT) ? (int)(pk & 1023u) : idx_final[m];
    const float4* tr = (const float4*)(table + (size_t)bi * D_OUT);
    const float4* br = (const float4*)bias;
    float4* orow = (float4*)(out + (size_t)m * D_OUT);
#pragma unroll
    for (int i = 0; i < 4; ++i) {
        const float4 tv = tr[l + i * 64];
        const float4 bv = br[l + i * 64];
        orow[l + i * 64] = make_float4(tv.x + bv.x, tv.y + bv.y,
                                       tv.z + bv.z, tv.w + bv.w);
    }
}

// ---------------------------------------------------------------------------
// Launch. Workspace map (byte offsets; total ~38.3 MB, harness ws >= ~98 MB):
//   Xh       0           33,554,432
//   Ch       33,554,432   2,097,152
//   x_sq     35,651,584      65,536
//   c_sq     35,717,120       4,096
//   pt1      35,721,216   1,048,576  (u64 [8][16384])
//   pt2      36,769,792   1,048,576
//   pt3      37,818,368   1,048,576
//   idx_fin  38,866,944      65,536
//   packed   38,932,480     131,072  (u64 [16384])
//   work     39,063,552   1,048,576  (16384*16*4, exact worst case)
//   ovf_list 40,112,128      65,536
//   ctrs     40,177,664         520  (wcount, ovfcount, done[128])
// ---------------------------------------------------------------------------
extern "C" void kernel_launch(void* const* d_in, const int* in_sizes, int n_in,
                              void* d_out, int out_size, void* d_ws, size_t ws_size,
                              hipStream_t stream)
{
    const float* X     = (const float*)d_in[0];
    const float* C     = (const float*)d_in[1];
    const float* table = (const float*)d_in[2];
    const float* bias  = (const float*)d_in[3];
    float* out = (float*)d_out;

    char* ws = (char*)d_ws;
    u16*   Xh       = (u16*)(ws);
    u16*   Ch       = (u16*)(ws + 33554432);
    float* x_sq     = (float*)(ws + 35651584);
    float* c_sq     = (float*)(ws + 35717120);
    u64*   pt1      = (u64*)(ws + 35721216);
    u64*   pt2      = (u64*)(ws + 36769792);
    u64*   pt3      = (u64*)(ws + 37818368);
    int*   idx_fin  = (int*)(ws + 38866944);
    u64*   packed   = (u64*)(ws + 38932480);
    u32*   work     = (u32*)(ws + 39063552);
    int*   ovf_list = (int*)(ws + 40112128);
    int*   ctrs     = (int*)(ws + 40177664);

    prep_kernel<<<(N_TOK + N_CENT) / 4, 256, 0, stream>>>(X, C, Xh, Ch,
                                                          x_sq, c_sq, ctrs);

    dim3 grid(N_TOK / BM, N_CENT / BN);   // 128 x 8
    gemm_fused_kernel<<<grid, 256, 0, stream>>>(Xh, Ch, x_sq, c_sq,
                                                pt1, pt2, pt3,
                                                idx_fin, packed,
                                                work, ovf_list, ctrs);

    rescore_kernel<<<2048, 256, 0, stream>>>(X, C, x_sq, c_sq,
                                             work, ovf_list, ctrs, packed);

    gather_kernel<<<N_TOK / 4, 256, 0, stream>>>(idx_fin, packed, table, bias, out);
}

// Round 9
// 227.452 us; speedup vs baseline: 1.2305x; 1.2305x over previous
//
#include <hip/hip_runtime.h>
#include <math.h>

// Problem constants
#define N_TOK  16384   // B*S
#define D_IN   1024
#define D_OUT  1024
#define N_CENT 1024

// GEMM tiling (BK=32: R3 measured 59.9us vs 64.6 at BK=64)
#define BM 128
#define BN 128
#define BK 32
#define NTILE (N_CENT / BN)   // 8

// Margin: bf16 approx error on d2 max ~1.6e-2 over all pairs; TAU >= 2*maxerr
// guarantees (a) unique-gap argmin exact, (b) candidate set {d2a <= gmin+TAU}
// contains the exact argmin. TAU=0.05 validated R3/R4/R5/R7/R8 (absmax 0).
#define TAU 0.05f

#define SENT 0xFFFFFFFFFFFFFFFFull

typedef __attribute__((ext_vector_type(8))) short short8;
typedef __attribute__((ext_vector_type(4))) float float4v;
typedef unsigned int u32;
typedef unsigned short u16;
typedef unsigned long long u64;

__device__ __forceinline__ void async_copy16(const void* g, void* l) {
    __builtin_amdgcn_global_load_lds(
        (const __attribute__((address_space(1))) u32*)g,
        (__attribute__((address_space(3))) u32*)l, 16, 0, 0);
}

__device__ __forceinline__ u16 f32_to_bf16_rne(float f) {
    u32 u = __float_as_uint(f);
    u32 r = (u + 0x7FFFu + ((u >> 16) & 1u)) >> 16;
    return (u16)r;
}

__device__ __forceinline__ u64 umin64(u64 a, u64 b) { return a < b ? a : b; }
__device__ __forceinline__ u64 umax64(u64 a, u64 b) { return a > b ? a : b; }
__device__ __forceinline__ float pk_val(u64 p) { return __uint_as_float((u32)(p >> 32)); }

// Merge two ascending-sorted u64 triples into (s1,s2,s3).
// Packed key (d2_bits<<32)|idx with d2>0: u64 order == lex (val, idx) ==
// numpy first-occurrence argmin tie-break. (R8-validated, absmax 0.)
__device__ __forceinline__ void merge3u(
    u64& s1, u64& s2, u64& s3, u64 b1, u64 b2, u64 b3)
{
    const u64 m1 = umin64(s1, b1);
    const u64 M1 = umax64(s1, b1);
    const u64 m2 = umin64(s2, b2);
    const u64 m3 = umin64(s3, b3);
    s1 = m1;
    const u64 t2 = umin64(M1, m2);
    s3 = umin64(umax64(M1, m2), m3);
    s2 = t2;
}

// Wave dot product, summation order identical to R5/R7/R8-validated rescore.
__device__ __forceinline__ float wave_dot(
    const float* __restrict__ X, const float* __restrict__ C,
    int m, int n, int l)
{
    const float4* xr = (const float4*)(X + (size_t)m * D_IN);
    const float4* cr = (const float4*)(C + (size_t)n * D_IN);
    float p = 0.f;
#pragma unroll
    for (int k = 0; k < 4; ++k) {
        const float4 cv = cr[l + 64 * k];
        const float4 xv = xr[l + 64 * k];
        p = fmaf(xv.x, cv.x, p); p = fmaf(xv.y, cv.y, p);
        p = fmaf(xv.z, cv.z, p); p = fmaf(xv.w, cv.w, p);
    }
#pragma unroll
    for (int off = 32; off > 0; off >>= 1) p += __shfl_xor(p, off);
    return p;
}

// ---------------------------------------------------------------------------
// Fused fp32->bf16 convert + row norms for X and C + counter zeroing.
// (Counter zeroing is visible to the later reduce_kernel via the kernel
// boundary's implicit device-scope release -- no fences needed.)
// ---------------------------------------------------------------------------
__global__ __launch_bounds__(256) void prep_kernel(
    const float* __restrict__ X, const float* __restrict__ C,
    u16* __restrict__ Xh, u16* __restrict__ Ch,
    float* __restrict__ xsq, float* __restrict__ csq,
    int* __restrict__ ctrs)
{
    if (blockIdx.x == 0 && threadIdx.x < 2) ctrs[threadIdx.x] = 0;

    const int wv = threadIdx.x >> 6;
    const int l  = threadIdx.x & 63;
    int row = blockIdx.x * 4 + wv;
    const float* src; u16* dsth; float* dsts;
    if (row < N_TOK) { src = X; dsth = Xh; dsts = xsq; }
    else { row -= N_TOK; src = C; dsth = Ch; dsts = csq; }
    const float4* xr = (const float4*)(src + (size_t)row * D_IN);
    ushort4* hr = (ushort4*)(dsth + (size_t)row * D_IN);
    float s = 0.f;
#pragma unroll
    for (int i = 0; i < 4; ++i) {
        float4 v = xr[l + i * 64];
        ushort4 o;
        o.x = f32_to_bf16_rne(v.x); o.y = f32_to_bf16_rne(v.y);
        o.z = f32_to_bf16_rne(v.z); o.w = f32_to_bf16_rne(v.w);
        hr[l + i * 64] = o;
        s += v.x * v.x + v.y * v.y + v.z * v.z + v.w * v.w;
    }
#pragma unroll
    for (int off = 32; off > 0; off >>= 1) s += __shfl_down(s, off);
    if (l == 0) dsts[row] = s;
}

// ---------------------------------------------------------------------------
// bf16 MFMA GEMM (BK=32, R3-proven staging) + fused per-tile top-3 epilogue
// (u64-packed, R8-proven). No cross-workgroup fencing (R8 lesson).
// ---------------------------------------------------------------------------
__global__ __launch_bounds__(256) void gemm_top3_kernel(
    const u16* __restrict__ Xh, const u16* __restrict__ Ch,
    const float* __restrict__ x_sq, const float* __restrict__ c_sq,
    u64* __restrict__ pt1, u64* __restrict__ pt2, u64* __restrict__ pt3)
{
    __shared__ __align__(16) u16 As[BM * BK];   // 8 KB
    __shared__ __align__(16) u16 Bs[BN * BK];   // 8 KB

    const int t  = threadIdx.x;
    const int w  = t >> 6;
    const int l  = t & 63;
    const int wi = w >> 1, wj = w & 1;
    const int m0 = blockIdx.x * BM;
    const int n0 = blockIdx.y * BN;
    const int quad = l >> 4;
    const int r15  = l & 15;

    float4v acc[4][4];
#pragma unroll
    for (int i = 0; i < 4; ++i)
#pragma unroll
        for (int j = 0; j < 4; ++j)
            acc[i][j] = (float4v){0.f, 0.f, 0.f, 0.f};

    for (int k0 = 0; k0 < D_IN; k0 += BK) {
        // 512 16B slots per operand: slot s -> row r=s>>2, lds-octet s&3,
        // global octet (s&3)^(r&3).  (R3-validated swizzle)
#pragma unroll
        for (int rnd = 0; rnd < 2; ++rnd) {
            const int s = rnd * 256 + t;
            const int r = s >> 2;
            const int q = (s & 3) ^ (r & 3);
            async_copy16(Xh + (size_t)(m0 + r) * D_IN + k0 + q * 8, As + s * 8);
            async_copy16(Ch + (size_t)(n0 + r) * D_IN + k0 + q * 8, Bs + s * 8);
        }
        __syncthreads();

        short8 af[4], bfr[4];
#pragma unroll
        for (int i = 0; i < 4; ++i) {
            const int r = wi * 64 + i * 16 + r15;
            af[i] = *(const short8*)(As + (r * 4 + (quad ^ (r & 3))) * 8);
        }
#pragma unroll
        for (int j = 0; j < 4; ++j) {
            const int r = wj * 64 + j * 16 + r15;
            bfr[j] = *(const short8*)(Bs + (r * 4 + (quad ^ (r & 3))) * 8);
        }
#pragma unroll
        for (int i = 0; i < 4; ++i)
#pragma unroll
            for (int j = 0; j < 4; ++j)
                acc[i][j] = __builtin_amdgcn_mfma_f32_16x16x32_bf16(
                    af[i], bfr[j], acc[i][j], 0, 0, 0);
        __syncthreads();
    }

    // Epilogue: per-64-col-subtile top-3 (u64-packed), cross-wave merge.
    u64* red = (u64*)As;   // [BM][2] triples = 6144 B, reuses staging arena

    const int nbase = n0 + wj * 64 + r15;
    float cq[4];
#pragma unroll
    for (int j = 0; j < 4; ++j) cq[j] = c_sq[nbase + j * 16];

#pragma unroll
    for (int i = 0; i < 4; ++i) {
#pragma unroll
        for (int reg = 0; reg < 4; ++reg) {
            const int rloc = wi * 64 + i * 16 + quad * 4 + reg;
            const float xq = x_sq[m0 + rloc];
            const float d0 = (xq - 2.0f * acc[i][0][reg]) + cq[0];
            u64 s1 = ((u64)__float_as_uint(d0) << 32) | (u32)nbase;
            u64 s2 = SENT, s3 = SENT;
#pragma unroll
            for (int j = 1; j < 4; ++j) {
                const float dj = (xq - 2.0f * acc[i][j][reg]) + cq[j];
                const u64 v = ((u64)__float_as_uint(dj) << 32) | (u32)(nbase + j * 16);
                if (v < s1)      { s3 = s2; s2 = s1; s1 = v; }
                else if (v < s2) { s3 = s2; s2 = v; }
                else if (v < s3) { s3 = v; }
            }
#pragma unroll
            for (int off = 1; off < 16; off <<= 1) {
                const u64 b1 = __shfl_xor(s1, off);
                const u64 b2 = __shfl_xor(s2, off);
                const u64 b3 = __shfl_xor(s3, off);
                merge3u(s1, s2, s3, b1, b2, b3);
            }
            if (r15 == 0) {
                red[(rloc * 2 + wj) * 3 + 0] = s1;
                red[(rloc * 2 + wj) * 3 + 1] = s2;
                red[(rloc * 2 + wj) * 3 + 2] = s3;
            }
        }
    }
    __syncthreads();
    if (t < BM) {
        u64 a1 = red[(t * 2) * 3], a2 = red[(t * 2) * 3 + 1], a3 = red[(t * 2) * 3 + 2];
        merge3u(a1, a2, a3,
                red[(t * 2 + 1) * 3], red[(t * 2 + 1) * 3 + 1], red[(t * 2 + 1) * 3 + 2]);
        const size_t o = (size_t)blockIdx.y * N_TOK + m0 + t;
        pt1[o] = a1; pt2[o] = a2; pt3[o] = a3;
    }
}

// ---------------------------------------------------------------------------
// Per-token merge of NTILE tile top-3 triples (u64). Builds bounded work
// list (<=16 items/token) and ovf list. Completeness exact: tile top-2
// union covers everything <= gmin+TAU iff no tile v3 <= thr. (R8 logic)
// ---------------------------------------------------------------------------
__global__ __launch_bounds__(256) void reduce_kernel(
    const u64* __restrict__ pt1, const u64* __restrict__ pt2,
    const u64* __restrict__ pt3,
    int* __restrict__ idx_final, u64* __restrict__ packed,
    u32* __restrict__ work, int* __restrict__ ovf_list,
    int* __restrict__ ctrs)
{
    const int m = blockIdx.x * 256 + threadIdx.x;
    u64 t1[NTILE], t2[NTILE], t3[NTILE];
#pragma unroll
    for (int q = 0; q < NTILE; ++q) {
        t1[q] = pt1[(size_t)q * N_TOK + m];
        t2[q] = pt2[(size_t)q * N_TOK + m];
        t3[q] = pt3[(size_t)q * N_TOK + m];
    }
    u64 g1 = t1[0], g2 = t2[0], g3 = t3[0];
#pragma unroll
    for (int q = 1; q < NTILE; ++q) merge3u(g1, g2, g3, t1[q], t2[q], t3[q]);

    const float thr = pk_val(g1) + TAU;
    idx_final[m] = (int)(g1 & 1023u);
    packed[m] = SENT;

    bool ovf = false;
#pragma unroll
    for (int q = 0; q < NTILE; ++q)
        if (pk_val(t3[q]) <= thr) ovf = true;

    if (ovf) {
        const int pos = atomicAdd(&ctrs[1], 1);
        ovf_list[pos] = m;
    } else if (pk_val(g2) <= thr) {
        int k = 0; u32 cd[2 * NTILE];
#pragma unroll
        for (int q = 0; q < NTILE; ++q) {
            if (pk_val(t1[q]) <= thr) cd[k++] = (u32)(t1[q] & 1023u);
            if (pk_val(t2[q]) <= thr) cd[k++] = (u32)(t2[q] & 1023u);
        }
        const int base = atomicAdd(&ctrs[0], k);
        for (int i = 0; i < k; ++i)
            work[base + i] = ((u32)m << 10) | cd[i];
    }
}

// ---------------------------------------------------------------------------
// Exact fp32 rescore, unified cand+ovf item space, one wave per item.
// u64 atomicMin == lex (val, idx). (R7/R8-validated)
// ---------------------------------------------------------------------------
__global__ __launch_bounds__(256) void rescore_kernel(
    const float* __restrict__ X, const float* __restrict__ C,
    const float* __restrict__ x_sq, const float* __restrict__ c_sq,
    const u32* __restrict__ work, const int* __restrict__ ovf_list,
    const int* __restrict__ ctrs, u64* __restrict__ packed)
{
    const int l = threadIdx.x & 63;
    const int nw   = ctrs[0];
    const int novf = ctrs[1];
    const int total = nw + (novf << 10);
    const int wgid   = blockIdx.x * 4 + (threadIdx.x >> 6);
    const int nwaves = gridDim.x * 4;

    for (int i = wgid; i < total; i += nwaves) {
        int m, n;
        if (i < nw) {
            const u32 item = work[i];
            m = (int)(item >> 10); n = (int)(item & 1023u);
        } else {
            const int j = i - nw;
            m = ovf_list[j >> 10]; n = j & 1023;
        }
        const float p = wave_dot(X, C, m, n, l);
        if (l == 0) {
            const float d2 = (x_sq[m] - 2.0f * p) + c_sq[n];
            const u64 pk = ((u64)__float_as_uint(d2) << 32) | (u32)n;
            atomicMin(&packed[m], pk);
        }
    }
}

// ---------------------------------------------------------------------------
// Gather + bias with fused writeback. One wave per token. (R8-validated)
// ---------------------------------------------------------------------------
__global__ __launch_bounds__(256) void gather_kernel(
    const int* __restrict__ idx_final, const u64* __restrict__ packed,
    const float* __restrict__ table, const float* __restrict__ bias,
    float* __restrict__ out)
{
    const int wv = threadIdx.x >> 6;
    const int l  = threadIdx.x & 63;
    const int m  = blockIdx.x * 4 + wv;
    const u64 pk = packed[m];
    const int bi = (pk != SENT) ? (int)(pk & 1023u) : idx_final[m];
    const float4* tr = (const float4*)(table + (size_t)bi * D_OUT);
    const float4* br = (const float4*)bias;
    float4* orow = (float4*)(out + (size_t)m * D_OUT);
#pragma unroll
    for (int i = 0; i < 4; ++i) {
        const float4 tv = tr[l + i * 64];
        const float4 bv = br[l + i * 64];
        orow[l + i * 64] = make_float4(tv.x + bv.x, tv.y + bv.y,
                                       tv.z + bv.z, tv.w + bv.w);
    }
}

// ---------------------------------------------------------------------------
// Launch. Workspace map (byte offsets; total ~40.2 MB):
//   Xh       0           33,554,432
//   Ch       33,554,432   2,097,152
//   x_sq     35,651,584      65,536
//   c_sq     35,717,120       4,096
//   pt1      35,721,216   1,048,576  (u64 [8][16384])
//   pt2      36,769,792   1,048,576
//   pt3      37,818,368   1,048,576
//   idx_fin  38,866,944      65,536
//   packed   38,932,480     131,072  (u64 [16384])
//   work     39,063,552   1,048,576  (16384*16*4, exact worst case)
//   ovf_list 40,112,128      65,536
//   ctrs     40,177,664           8  (wcount, ovfcount)
// ---------------------------------------------------------------------------
extern "C" void kernel_launch(void* const* d_in, const int* in_sizes, int n_in,
                              void* d_out, int out_size, void* d_ws, size_t ws_size,
                              hipStream_t stream)
{
    const float* X     = (const float*)d_in[0];
    const float* C     = (const float*)d_in[1];
    const float* table = (const float*)d_in[2];
    const float* bias  = (const float*)d_in[3];
    float* out = (float*)d_out;

    char* ws = (char*)d_ws;
    u16*   Xh       = (u16*)(ws);
    u16*   Ch       = (u16*)(ws + 33554432);
    float* x_sq     = (float*)(ws + 35651584);
    float* c_sq     = (float*)(ws + 35717120);
    u64*   pt1      = (u64*)(ws + 35721216);
    u64*   pt2      = (u64*)(ws + 36769792);
    u64*   pt3      = (u64*)(ws + 37818368);
    int*   idx_fin  = (int*)(ws + 38866944);
    u64*   packed   = (u64*)(ws + 38932480);
    u32*   work     = (u32*)(ws + 39063552);
    int*   ovf_list = (int*)(ws + 40112128);
    int*   ctrs     = (int*)(ws + 40177664);

    prep_kernel<<<(N_TOK + N_CENT) / 4, 256, 0, stream>>>(X, C, Xh, Ch,
                                                          x_sq, c_sq, ctrs);

    dim3 grid(N_TOK / BM, N_CENT / BN);   // 128 x 8
    gemm_top3_kernel<<<grid, 256, 0, stream>>>(Xh, Ch, x_sq, c_sq,
                                               pt1, pt2, pt3);

    reduce_kernel<<<N_TOK / 256, 256, 0, stream>>>(pt1, pt2, pt3,
                                                   idx_fin, packed,
                                                   work, ovf_list, ctrs);

    rescore_kernel<<<2048, 256, 0, stream>>>(X, C, x_sq, c_sq,
                                             work, ovf_list, ctrs, packed);

    gather_kernel<<<N_TOK / 4, 256, 0, stream>>>(idx_fin, packed, table, bias, out);
}